// Round 6
// baseline (163.721 us; speedup 1.0000x reference)
//
#include <hip/hip_runtime.h>

// EdgeConv with KNN graph: B=8, N=4096, D=3, E=64, K=32.
// One wave per point-PAIR sweep. Batch staged in LDS as float4 (x,y,z,sq);
// sq uses the same fmaf chain as queries so self-dist is exactly 0.
//
// R5 post-mortem: LDS pipe is the bottleneck (~1550 cyc/pt: sweep 768,
// compaction 380, sorts 366). This version:
//  - 2 points per sweep, 16-bit truncated keys packed 2/reg (v_perm_b32):
//    sweep LDS reads halve. Truncation is monotone, so a threshold H16 with
//    count in [32,64] gives a pool SUPERSET of the exact top-32; the final
//    sort uses exact recomputed fp32 keys + index => selection identical to
//    jax.lax.top_k (incl. lower-index tie-break).
//  - compaction writes index only (1 ds_write/group, exact key recomputed
//    from one divergent ds_read_b128).
//  - partial bitonic (16 stages, not 21): top-32 lands in lanes 0..31
//    UNORDERED -- the epilogue max doesn't need order.
//  - packed u16 minima bitonic (pair 0 only) seeds both thresholds; pair 1
//    reuses converged H values (~1 probe).
// SPILL DISCIPLINE (R2/R3): pk[] in VGPRs only with FULL unroll of every
// loop touching it + (512,4) 128-VGPR budget.

#define NPTS 4096
#define KNN  32

#define WFENCE() __asm__ volatile("s_waitcnt lgkmcnt(0)" ::: "memory")

typedef unsigned short u16x2 __attribute__((ext_vector_type(2)));

__device__ __forceinline__ unsigned lane_prefix(unsigned long long m) {
    return __builtin_amdgcn_mbcnt_hi((unsigned)(m >> 32),
           __builtin_amdgcn_mbcnt_lo((unsigned)m, 0u));
}
__device__ __forceinline__ unsigned pk_min_u16(unsigned a, unsigned b) {
    return __builtin_bit_cast(unsigned, __builtin_elementwise_min(
        __builtin_bit_cast(u16x2, a), __builtin_bit_cast(u16x2, b)));
}
__device__ __forceinline__ unsigned pk_max_u16(unsigned a, unsigned b) {
    return __builtin_bit_cast(unsigned, __builtin_elementwise_max(
        __builtin_bit_cast(u16x2, a), __builtin_bit_cast(u16x2, b)));
}

__global__ __launch_bounds__(512, 4)
void edgeconv_knn_kernel(const float* __restrict__ x,
                         const float* __restrict__ theta_w,
                         const float* __restrict__ theta_b,
                         const float* __restrict__ phi_w,
                         const float* __restrict__ phi_b,
                         float* __restrict__ out)
{
    __shared__ float4 s_p[NPTS];               // 64 KB: x,y,z,sq
    __shared__ unsigned s_pool[8][64];         // 2 KB: per-wave pool indices

    const int tid  = threadIdx.x;
    const int wv   = tid >> 6;
    const int lane = tid & 63;

    const int b  = blockIdx.x >> 7;            // 128 WGs per batch
    const int i0 = (blockIdx.x & 127) << 5;    // 32 points per WG (4/wave)

    // lane == output channel e
    const float tw0 = theta_w[lane];
    const float tw1 = theta_w[64 + lane];
    const float tw2 = theta_w[128 + lane];
    const float tbv = theta_b[lane];
    const float pw0 = phi_w[lane];
    const float pw1 = phi_w[64 + lane];
    const float pw2 = phi_w[128 + lane];
    const float pbv = phi_b[lane];

    const float* xb = x + (size_t)b * NPTS * 3;
    for (int p = tid; p < NPTS; p += 512) {
        const float px = xb[p * 3 + 0];
        const float py = xb[p * 3 + 1];
        const float pz = xb[p * 3 + 2];
        const float sq = fmaf(pz, pz, fmaf(py, py, px * px));
        s_p[p] = make_float4(px, py, pz, sq);
    }
    __syncthreads();

    unsigned HA = 0u, HB = 0u;                 // carried 16-bit thresholds

    for (int pair = 0; pair < 2; ++pair) {
        const int iA = i0 + wv * 4 + pair * 2;
        const int iB = iA + 1;
        const float4 PA = s_p[iA];
        const float4 PB = s_p[iB];

        // ---- sweep: distances for A and B, 16-bit keys packed 2/reg ----
        unsigned pk[64];
        unsigned pmin = 0xFFFFFFFFu;
        #pragma unroll
        for (int s = 0; s < 64; ++s) {
            const float4 Q = s_p[(s << 6) + lane];
            const float dtA = fmaf(PA.z, Q.z, fmaf(PA.y, Q.y, PA.x * Q.x));
            float dA = (PA.w + Q.w) - 2.0f * dtA;
            dA = fmaxf(dA, 0.0f);
            const float dtB = fmaf(PB.z, Q.z, fmaf(PB.y, Q.y, PB.x * Q.x));
            float dB = (PB.w + Q.w) - 2.0f * dtB;
            dB = fmaxf(dB, 0.0f);
            // low16 = top16 of A, high16 = top16 of B
            pk[s] = __builtin_amdgcn_perm(__float_as_uint(dB),
                                          __float_as_uint(dA), 0x07060302u);
            pmin = pk_min_u16(pmin, pk[s]);
        }

        if (pair == 0) {
            // packed bitonic sort of lane minima (both halves independently)
            unsigned v = pmin;
            #pragma unroll
            for (int k = 2; k <= 64; k <<= 1) {
                #pragma unroll
                for (int jj = k >> 1; jj >= 1; jj >>= 1) {
                    const unsigned o  = (unsigned)__shfl_xor((int)v, jj, 64);
                    const unsigned mn = pk_min_u16(v, o);
                    const unsigned mx = pk_max_u16(v, o);
                    const bool wantmin = (((lane & k) == 0) == ((lane & jj) == 0));
                    v = wantmin ? mn : mx;
                }
            }
            const unsigned v32 = (unsigned)__builtin_amdgcn_readlane((int)v, 32);
            HA = v32 & 0xFFFFu;                // 33rd-smallest lane-min, point A
            HB = v32 >> 16;                    // point B
        }

        #pragma unroll
        for (int half = 0; half < 2; ++half) {
            const bool hi   = (half == 1);
            const float4 PX = hi ? PB : PA;
            const int   iX  = hi ? iB : iA;

            auto cnt_lt = [&](unsigned T) -> unsigned {
                unsigned c = 0;
                #pragma unroll
                for (int s = 0; s < 64; ++s) {
                    const unsigned kk = hi ? (pk[s] >> 16) : (pk[s] & 0xFFFFu);
                    c += (unsigned)__popcll(__ballot(kk < T));
                }
                return c;
            };

            // ---- threshold search in 16-bit key space ----
            unsigned H = hi ? HB : HA;
            unsigned L = 0u;
            unsigned c = cnt_lt(H);
            if (c < KNN) {                     // raise by octaves (exp LSB = bit 7)
                unsigned step = 0x80u;
                do {
                    unsigned Hn = H + step;
                    if (Hn > 0x8000u) Hn = 0x8000u;
                    L = H; H = Hn; step <<= 1;
                    c = cnt_lt(H);
                } while (c < KNN);
            }
            while (c > 64u && (H - L) > 1u) {
                const unsigned M  = L + ((H - L) >> 1);
                const unsigned cm = cnt_lt(M);
                if (cm >= KNN) { H = M; c = cm; } else { L = M; }
            }
            if (hi) HB = H; else HA = H;       // carry to next pair

            // ---- compaction: survivor INDICES only ----
            WFENCE();
            unsigned base = 0;
            #pragma unroll
            for (int s = 0; s < 64; ++s) {
                const unsigned kk = hi ? (pk[s] >> 16) : (pk[s] & 0xFFFFu);
                const bool pred = kk < H;
                const unsigned long long bm = __ballot(pred);
                if (bm) {
                    if (pred) {
                        const unsigned pos = base + lane_prefix(bm);
                        if (pos < 64u) s_pool[wv][pos] = (unsigned)((s << 6) + lane);
                    }
                    base += (unsigned)__popcll(bm);
                }
            }
            WFENCE();
            const unsigned m = base < 64u ? base : 64u;   // m >= 32 guaranteed

            // ---- exact keys for pool members (same fmaf chain) ----
            unsigned myk = 0xFFFFFFFFu;
            unsigned myj = 0u;                 // sentinel; never selected (m>=32)
            if ((unsigned)lane < m) {
                myj = s_pool[wv][lane];
                const float4 Q = s_p[myj];
                const float dt = fmaf(PX.z, Q.z, fmaf(PX.y, Q.y, PX.x * Q.x));
                float d = (PX.w + Q.w) - 2.0f * dt;
                d = fmaxf(d, 0.0f);
                myk = __float_as_uint(d);
            }

            // ---- partial bitonic: 32-sorts (k=2..32) + one merge step ----
            #pragma unroll
            for (int k = 2; k <= 32; k <<= 1) {
                #pragma unroll
                for (int jj = k >> 1; jj >= 1; jj >>= 1) {
                    const unsigned ok = (unsigned)__shfl_xor((int)myk, jj, 64);
                    const unsigned oj = (unsigned)__shfl_xor((int)myj, jj, 64);
                    const bool wantmin = (((lane & k) == 0) == ((lane & jj) == 0));
                    const bool less = (myk < ok) || (myk == ok && myj < oj);
                    if (less != wantmin) { myk = ok; myj = oj; }
                }
            }
            {   // k=64, jj=32 only: lanes 0..31 <- 32 smallest (unordered)
                const unsigned ok = (unsigned)__shfl_xor((int)myk, 32, 64);
                const unsigned oj = (unsigned)__shfl_xor((int)myj, 32, 64);
                const bool wantmin = ((lane & 32) == 0);
                const bool less = (myk < ok) || (myk == ok && myj < oj);
                if (less != wantmin) { myk = ok; myj = oj; }
            }

            // ---- epilogue: lane = channel e; max over the 32 selected ----
            float dx = 0.f, dy = 0.f, dz = 0.f;
            if (lane < KNN) {
                const float4 Q = s_p[myj];
                dx = Q.x - PX.x; dy = Q.y - PX.y; dz = Q.z - PX.z;
            }
            const float basev = tbv + pbv + fmaf(pw2, PX.z, fmaf(pw1, PX.y, pw0 * PX.x));
            float mx = -3.0e38f;
            #pragma unroll
            for (int t = 0; t < KNN; ++t) {
                const float ndx = __builtin_bit_cast(float, __builtin_amdgcn_readlane(__builtin_bit_cast(int, dx), t));
                const float ndy = __builtin_bit_cast(float, __builtin_amdgcn_readlane(__builtin_bit_cast(int, dy), t));
                const float ndz = __builtin_bit_cast(float, __builtin_amdgcn_readlane(__builtin_bit_cast(int, dz), t));
                const float proj = fmaf(tw2, ndz, fmaf(tw1, ndy, tw0 * ndx));
                mx = fmaxf(mx, proj);
            }
            out[(((size_t)b * NPTS + (size_t)iX) << 6) + lane] = mx + basev;
        }
    }
}

extern "C" void kernel_launch(void* const* d_in, const int* in_sizes, int n_in,
                              void* d_out, int out_size, void* d_ws, size_t ws_size,
                              hipStream_t stream) {
    const float* x  = (const float*)d_in[0];
    const float* tw = (const float*)d_in[1];
    const float* tb = (const float*)d_in[2];
    const float* pw = (const float*)d_in[3];
    const float* pb = (const float*)d_in[4];
    float* out = (float*)d_out;

    dim3 grid(8 * (NPTS / 32));   // 1024 WGs: 128 per batch, 32 points each
    dim3 block(512);
    hipLaunchKernelGGL(edgeconv_knn_kernel, grid, block, 0, stream,
                       x, tw, tb, pw, pb, out);
}

// Round 7
// 162.546 us; speedup vs baseline: 1.0072x; 1.0072x over previous
//
#include <hip/hip_runtime.h>

// EdgeConv with KNN graph: B=8, N=4096, D=3, E=64, K=32.
// R6 post-mortem: NOT LDS-throughput-bound -- VALU + dependency-stall bound
// at 16 waves/CU (dual cap: 70KB LDS -> 2 blocks; 128 unified VGPR+AGPR ->
// 4 waves/SIMD). This version breaks BOTH caps -> 24 waves/CU:
//  - 64 candidate keys TRUNCATED to 16 bits, packed 2/reg: pk[32] -> wave
//    fits the (512,6) 85-VGPR budget. Monotone truncation => threshold pool
//    is a SUPERSET of the exact top-32 (proof in R6); final selection sorts
//    exact recomputed fp32 keys + index => identical to jax.lax.top_k incl.
//    lower-index tie-break.
//  - LDS 50KB: float2 xy (32K) + float z (16K) + index-only pool (2K);
//    sq recomputed per candidate with the SAME fmaf chain as the reference
//    formula (self-dist exactly 0; selection set bit-faithful).
// SPILL DISCIPLINE (R2/R3): pk[] in VGPRs only with FULL unroll of every
// loop touching it; tripwire = FETCH_SIZE explosion.

#define NPTS 4096
#define KNN  32

#define WFENCE() __asm__ volatile("s_waitcnt lgkmcnt(0)" ::: "memory")

typedef unsigned short u16x2 __attribute__((ext_vector_type(2)));

__device__ __forceinline__ unsigned lane_prefix(unsigned long long m) {
    return __builtin_amdgcn_mbcnt_hi((unsigned)(m >> 32),
           __builtin_amdgcn_mbcnt_lo((unsigned)m, 0u));
}
__device__ __forceinline__ unsigned pk_min_u16(unsigned a, unsigned b) {
    return __builtin_bit_cast(unsigned, __builtin_elementwise_min(
        __builtin_bit_cast(u16x2, a), __builtin_bit_cast(u16x2, b)));
}

__global__ __launch_bounds__(512, 6)
void edgeconv_knn_kernel(const float* __restrict__ x,
                         const float* __restrict__ theta_w,
                         const float* __restrict__ theta_b,
                         const float* __restrict__ phi_w,
                         const float* __restrict__ phi_b,
                         float* __restrict__ out)
{
    __shared__ float2   s_xy[NPTS];        // 32 KB
    __shared__ float    s_z[NPTS];         // 16 KB
    __shared__ unsigned s_pool[8][64];     // 2 KB: per-wave survivor indices

    const int tid  = threadIdx.x;
    const int wv   = tid >> 6;
    const int lane = tid & 63;

    const int b  = blockIdx.x >> 7;        // 128 WGs per batch
    const int i0 = (blockIdx.x & 127) << 5;// 32 points per WG (4 per wave)

    // lane == output channel e
    const float tw0 = theta_w[lane];
    const float tw1 = theta_w[64 + lane];
    const float tw2 = theta_w[128 + lane];
    const float tbv = theta_b[lane];
    const float pw0 = phi_w[lane];
    const float pw1 = phi_w[64 + lane];
    const float pw2 = phi_w[128 + lane];
    const float pbv = phi_b[lane];

    const float* xb = x + (size_t)b * NPTS * 3;
    for (int p = tid; p < NPTS; p += 512) {
        s_xy[p] = make_float2(xb[p * 3 + 0], xb[p * 3 + 1]);
        s_z[p]  = xb[p * 3 + 2];
    }
    __syncthreads();

    for (int r = 0; r < 4; ++r) {
        const int i = i0 + wv * 4 + r;
        const float2 pxy = s_xy[i];
        const float  pz  = s_z[i];
        const float  sqi = fmaf(pz, pz, fmaf(pxy.y, pxy.y, pxy.x * pxy.x));

        // ---- sweep: 64 keys/lane, truncated u16, packed 2/reg ----
        unsigned pk[32];
        unsigned pmin = 0xFFFFFFFFu;
        #pragma unroll
        for (int t = 0; t < 32; ++t) {
            const int j0 = ((2 * t)     << 6) + lane;
            const int j1 = ((2 * t + 1) << 6) + lane;
            const float2 q0 = s_xy[j0]; const float qz0 = s_z[j0];
            const float2 q1 = s_xy[j1]; const float qz1 = s_z[j1];
            const float sq0 = fmaf(qz0, qz0, fmaf(q0.y, q0.y, q0.x * q0.x));
            const float dt0 = fmaf(pz,  qz0, fmaf(pxy.y, q0.y, pxy.x * q0.x));
            float d0 = (sqi + sq0) - 2.0f * dt0;
            d0 = fmaxf(d0, 0.0f);
            const float sq1 = fmaf(qz1, qz1, fmaf(q1.y, q1.y, q1.x * q1.x));
            const float dt1 = fmaf(pz,  qz1, fmaf(pxy.y, q1.y, pxy.x * q1.x));
            float d1 = (sqi + sq1) - 2.0f * dt1;
            d1 = fmaxf(d1, 0.0f);
            // lo16 = top16(d0), hi16 = top16(d1)
            pk[t] = __builtin_amdgcn_perm(__float_as_uint(d1),
                                          __float_as_uint(d0), 0x07060302u);
            pmin = pk_min_u16(pmin, pk[t]);
        }
        unsigned mn = min(pmin & 0xFFFFu, pmin >> 16);   // per-lane min (u16)

        // ---- bitonic sort of 64 lane-minima -> sampled threshold ----
        #pragma unroll
        for (int k = 2; k <= 64; k <<= 1) {
            #pragma unroll
            for (int jj = k >> 1; jj >= 1; jj >>= 1) {
                const unsigned o = (unsigned)__shfl_xor((int)mn, jj, 64);
                const bool wantmin = (((lane & k) == 0) == ((lane & jj) == 0));
                const bool less = (mn < o);
                if (less != wantmin) mn = o;
            }
        }
        unsigned H = (unsigned)__builtin_amdgcn_readlane((int)mn, 32);

        // wave-uniform count of u16 keys strictly below T
        auto cnt_lt = [&](unsigned T) -> unsigned {
            unsigned c = 0;
            #pragma unroll
            for (int t = 0; t < 32; ++t) {
                c += (unsigned)__popcll(__ballot((pk[t] & 0xFFFFu) < T));
                c += (unsigned)__popcll(__ballot((pk[t] >> 16)     < T));
            }
            return c;
        };

        // ---- threshold search in 16-bit key space ----
        unsigned L = 0u;
        unsigned c = cnt_lt(H);
        if (c < KNN) {                       // raise by octaves (exp LSB = bit 7)
            unsigned step = 0x80u;
            do {
                unsigned Hn = H + step;
                if (Hn > 0x8000u) Hn = 0x8000u;
                L = H; H = Hn; step <<= 1;
                c = cnt_lt(H);
            } while (c < KNN);
        }
        while (c > 64u && (H - L) > 1u) {
            const unsigned M  = L + ((H - L) >> 1);
            const unsigned cm = cnt_lt(M);
            if (cm >= KNN) { H = M; c = cm; } else { L = M; }
        }

        // ---- compaction: survivor indices only (ballot + mbcnt) ----
        WFENCE();                            // prior pool reads complete
        unsigned base = 0;
        #pragma unroll
        for (int s = 0; s < 64; ++s) {
            const unsigned kk = (s & 1) ? (pk[s >> 1] >> 16)
                                        : (pk[s >> 1] & 0xFFFFu);
            const bool pred = kk < H;
            const unsigned long long bm = __ballot(pred);
            if (bm) {
                if (pred) {
                    const unsigned pos = base + lane_prefix(bm);
                    if (pos < 64u) s_pool[wv][pos] = (unsigned)((s << 6) + lane);
                }
                base += (unsigned)__popcll(bm);
            }
        }
        WFENCE();
        const unsigned m = base < 64u ? base : 64u;   // m >= 32 guaranteed

        // ---- exact fp32 keys for pool members (same fmaf chain) ----
        unsigned myk = 0xFFFFFFFFu;
        unsigned myj = 0u;                   // sentinel, never selected (m>=32)
        if ((unsigned)lane < m) {
            myj = s_pool[wv][lane];
            const float2 q = s_xy[myj]; const float qz = s_z[myj];
            const float sqj = fmaf(qz, qz, fmaf(q.y, q.y, q.x * q.x));
            const float dt  = fmaf(pz, qz, fmaf(pxy.y, q.y, pxy.x * q.x));
            float d = (sqi + sqj) - 2.0f * dt;
            d = fmaxf(d, 0.0f);
            myk = __float_as_uint(d);
        }

        // ---- partial bitonic: 32-sorts + one merge -> bottom-32 unordered ----
        #pragma unroll
        for (int k = 2; k <= 32; k <<= 1) {
            #pragma unroll
            for (int jj = k >> 1; jj >= 1; jj >>= 1) {
                const unsigned ok = (unsigned)__shfl_xor((int)myk, jj, 64);
                const unsigned oj = (unsigned)__shfl_xor((int)myj, jj, 64);
                const bool wantmin = (((lane & k) == 0) == ((lane & jj) == 0));
                const bool less = (myk < ok) || (myk == ok && myj < oj);
                if (less != wantmin) { myk = ok; myj = oj; }
            }
        }
        {   // k=64, jj=32: lanes 0..31 <- the 32 smallest (unordered)
            const unsigned ok = (unsigned)__shfl_xor((int)myk, 32, 64);
            const unsigned oj = (unsigned)__shfl_xor((int)myj, 32, 64);
            const bool wantmin = ((lane & 32) == 0);
            const bool less = (myk < ok) || (myk == ok && myj < oj);
            if (less != wantmin) { myk = ok; myj = oj; }
        }

        // ---- epilogue: lane = channel e; max over the 32 selected ----
        float dx = 0.f, dy = 0.f, dz = 0.f;
        if (lane < KNN) {
            const float2 q = s_xy[myj];
            dx = q.x - pxy.x; dy = q.y - pxy.y; dz = s_z[myj] - pz;
        }
        const float basev = tbv + pbv + fmaf(pw2, pz, fmaf(pw1, pxy.y, pw0 * pxy.x));
        float mx = -3.0e38f;
        #pragma unroll
        for (int t = 0; t < KNN; ++t) {
            const float ndx = __builtin_bit_cast(float, __builtin_amdgcn_readlane(__builtin_bit_cast(int, dx), t));
            const float ndy = __builtin_bit_cast(float, __builtin_amdgcn_readlane(__builtin_bit_cast(int, dy), t));
            const float ndz = __builtin_bit_cast(float, __builtin_amdgcn_readlane(__builtin_bit_cast(int, dz), t));
            const float proj = fmaf(tw2, ndz, fmaf(tw1, ndy, tw0 * ndx));
            mx = fmaxf(mx, proj);
        }
        out[(((size_t)b * NPTS + (size_t)i) << 6) + lane] = mx + basev;
    }
}

extern "C" void kernel_launch(void* const* d_in, const int* in_sizes, int n_in,
                              void* d_out, int out_size, void* d_ws, size_t ws_size,
                              hipStream_t stream) {
    const float* x  = (const float*)d_in[0];
    const float* tw = (const float*)d_in[1];
    const float* tb = (const float*)d_in[2];
    const float* pw = (const float*)d_in[3];
    const float* pb = (const float*)d_in[4];
    float* out = (float*)d_out;

    dim3 grid(8 * (NPTS / 32));   // 1024 WGs: 128 per batch, 32 points each
    dim3 block(512);
    hipLaunchKernelGGL(edgeconv_knn_kernel, grid, block, 0, stream,
                       x, tw, tb, pw, pb, out);
}

// Round 8
// 144.979 us; speedup vs baseline: 1.1293x; 1.1212x over previous
//
#include <hip/hip_runtime.h>

// EdgeConv with KNN graph: B=8, N=4096, D=3, E=64, K=32.
// R7 post-mortem: VALU-issue bound; spill at 85-reg budget; key arrays get
// parked in AGPRs (v_accvgpr_* tax) when arch VGPRs are tight.
// This version:
//  - u16 truncated keys packed 2/reg: pk[32]. Total live regs ~80 under
//    (512,4) [128 budget] -> array in ARCH VGPRs, no AGPR moves, no spill.
//    Monotone truncation => threshold pool is a SUPERSET of exact top-32
//    (R6 proof); no exact-key ties across the pool boundary; final partial
//    bitonic sorts exact recomputed fp32 keys + index => selection identical
//    to jax.lax.top_k incl. lower-index tie-break.
//  - SoA planes s_x/s_y/s_z/s_sq (64 KB; sq precomputed once, same fmaf
//    chain as query -> self-dist exactly 0): sweep reads 4 consecutive
//    candidates per plane as b128 and computes TWO distances per packed op
//    (v_pk_fma_f32 via float2 elementwise builtins): sweep VALU ~halved.
//  - ballot counting + sampled threshold + index-only pool + partial
//    bitonic (16 stages) + readlane epilogue (all R4-R6 proven).
// SPILL DISCIPLINE (R2/R3): every loop touching pk[] is FULLY unrolled.

#define NPTS 4096
#define KNN  32

#define WFENCE() __asm__ volatile("s_waitcnt lgkmcnt(0)" ::: "memory")

typedef unsigned short u16x2 __attribute__((ext_vector_type(2)));
typedef float          f32x2 __attribute__((ext_vector_type(2)));

__device__ __forceinline__ unsigned lane_prefix(unsigned long long m) {
    return __builtin_amdgcn_mbcnt_hi((unsigned)(m >> 32),
           __builtin_amdgcn_mbcnt_lo((unsigned)m, 0u));
}
__device__ __forceinline__ unsigned pk_min_u16(unsigned a, unsigned b) {
    return __builtin_bit_cast(unsigned, __builtin_elementwise_min(
        __builtin_bit_cast(u16x2, a), __builtin_bit_cast(u16x2, b)));
}
// lo16 = top16(d0), hi16 = top16(d1)
__device__ __forceinline__ unsigned pack_keys(float d0, float d1) {
    return __builtin_amdgcn_perm(__builtin_bit_cast(unsigned, d1),
                                 __builtin_bit_cast(unsigned, d0), 0x07060302u);
}

__global__ __launch_bounds__(512, 4)
void edgeconv_knn_kernel(const float* __restrict__ x,
                         const float* __restrict__ theta_w,
                         const float* __restrict__ theta_b,
                         const float* __restrict__ phi_w,
                         const float* __restrict__ phi_b,
                         float* __restrict__ out)
{
    __shared__ float    s_x[NPTS];         // 16 KB each plane
    __shared__ float    s_y[NPTS];
    __shared__ float    s_z[NPTS];
    __shared__ float    s_sq[NPTS];
    __shared__ unsigned s_pool[8][64];     // 2 KB: per-wave survivor indices

    const int tid  = threadIdx.x;
    const int wv   = tid >> 6;
    const int lane = tid & 63;

    const int b  = blockIdx.x >> 7;        // 128 WGs per batch
    const int i0 = (blockIdx.x & 127) << 5;// 32 points per WG (4 per wave)

    // lane == output channel e
    const float tw0 = theta_w[lane];
    const float tw1 = theta_w[64 + lane];
    const float tw2 = theta_w[128 + lane];
    const float tbv = theta_b[lane];
    const float pw0 = phi_w[lane];
    const float pw1 = phi_w[64 + lane];
    const float pw2 = phi_w[128 + lane];
    const float pbv = phi_b[lane];

    const float* xb = x + (size_t)b * NPTS * 3;
    for (int p = tid; p < NPTS; p += 512) {
        const float px = xb[p * 3 + 0];
        const float py = xb[p * 3 + 1];
        const float pz = xb[p * 3 + 2];
        s_x[p] = px; s_y[p] = py; s_z[p] = pz;
        s_sq[p] = fmaf(pz, pz, fmaf(py, py, px * px));
    }
    __syncthreads();

    for (int r = 0; r < 4; ++r) {
        const int i = i0 + wv * 4 + r;
        const float px = s_x[i], py = s_y[i], pz = s_z[i], sqi = s_sq[i];
        const f32x2 PX2 = {px, px}, PY2 = {py, py}, PZ2 = {pz, pz};
        const f32x2 SQI2 = {sqi, sqi};
        const f32x2 N2   = {-2.0f, -2.0f};
        const f32x2 Z02  = {0.0f, 0.0f};

        // ---- sweep: lane owns candidates j = 256*t + 4*lane + {0..3} ----
        // pk[2t]   : cands +0,+1 (lo16,hi16); pk[2t+1]: cands +2,+3.
        // slot s=0..63 -> j = ((s>>2)<<8) + (lane<<2) + (s&3).
        unsigned pk[32];
        unsigned pmin = 0xFFFFFFFFu;
        #pragma unroll
        for (int t = 0; t < 16; ++t) {
            const int jb = (t << 8) + (lane << 2);
            const float4 QX = *(const float4*)&s_x[jb];
            const float4 QY = *(const float4*)&s_y[jb];
            const float4 QZ = *(const float4*)&s_z[jb];
            const float4 QS = *(const float4*)&s_sq[jb];
            const f32x2 X0 = {QX.x, QX.y}, X1 = {QX.z, QX.w};
            const f32x2 Y0 = {QY.x, QY.y}, Y1 = {QY.z, QY.w};
            const f32x2 Zc0 = {QZ.x, QZ.y}, Zc1 = {QZ.z, QZ.w};
            const f32x2 S0 = {QS.x, QS.y}, S1 = {QS.z, QS.w};
            const f32x2 dt0 = __builtin_elementwise_fma(PZ2, Zc0,
                              __builtin_elementwise_fma(PY2, Y0, PX2 * X0));
            const f32x2 dt1 = __builtin_elementwise_fma(PZ2, Zc1,
                              __builtin_elementwise_fma(PY2, Y1, PX2 * X1));
            f32x2 d0 = __builtin_elementwise_fma(N2, dt0, SQI2 + S0);
            f32x2 d1 = __builtin_elementwise_fma(N2, dt1, SQI2 + S1);
            d0 = __builtin_elementwise_max(d0, Z02);
            d1 = __builtin_elementwise_max(d1, Z02);
            pk[2 * t]     = pack_keys(d0.x, d0.y);
            pk[2 * t + 1] = pack_keys(d1.x, d1.y);
            pmin = pk_min_u16(pmin, pk[2 * t]);
            pmin = pk_min_u16(pmin, pk[2 * t + 1]);
        }
        unsigned mn = min(pmin & 0xFFFFu, pmin >> 16);   // per-lane min (u16)

        // ---- bitonic sort of 64 lane-minima -> sampled threshold ----
        #pragma unroll
        for (int k = 2; k <= 64; k <<= 1) {
            #pragma unroll
            for (int jj = k >> 1; jj >= 1; jj >>= 1) {
                const unsigned o = (unsigned)__shfl_xor((int)mn, jj, 64);
                const bool wantmin = (((lane & k) == 0) == ((lane & jj) == 0));
                const bool less = (mn < o);
                if (less != wantmin) mn = o;
            }
        }
        unsigned H = (unsigned)__builtin_amdgcn_readlane((int)mn, 32);

        // wave-uniform count of u16 keys strictly below T (ballot -> scalar)
        auto cnt_lt = [&](unsigned T) -> unsigned {
            unsigned c = 0;
            #pragma unroll
            for (int k2 = 0; k2 < 32; ++k2) {
                c += (unsigned)__popcll(__ballot((pk[k2] & 0xFFFFu) < T));
                c += (unsigned)__popcll(__ballot((pk[k2] >> 16)     < T));
            }
            return c;
        };

        // ---- threshold search in 16-bit key space ----
        unsigned L = 0u;
        unsigned c = cnt_lt(H);
        if (c < KNN) {                       // raise by octaves (exp LSB = 0x80)
            unsigned step = 0x80u;
            do {
                unsigned Hn = H + step;
                if (Hn > 0xFFFFu) Hn = 0xFFFFu;
                L = H; H = Hn; step <<= 1;
                c = cnt_lt(H);
            } while (c < KNN);
        }
        while (c > 64u && (H - L) > 1u) {
            const unsigned M  = L + ((H - L) >> 1);
            const unsigned cm = cnt_lt(M);
            if (cm >= KNN) { H = M; c = cm; } else { L = M; }
        }

        // ---- compaction: survivor indices only (ballot + mbcnt) ----
        WFENCE();                            // prior pool reads complete
        unsigned base = 0;
        #pragma unroll
        for (int s = 0; s < 64; ++s) {
            const unsigned kk = (s & 1) ? (pk[s >> 1] >> 16)
                                        : (pk[s >> 1] & 0xFFFFu);
            const bool pred = kk < H;
            const unsigned long long bm = __ballot(pred);
            if (bm) {
                if (pred) {
                    const unsigned pos = base + lane_prefix(bm);
                    if (pos < 64u)
                        s_pool[wv][pos] =
                            (unsigned)(((s >> 2) << 8) + (lane << 2) + (s & 3));
                }
                base += (unsigned)__popcll(bm);
            }
        }
        WFENCE();
        const unsigned m = base < 64u ? base : 64u;   // m >= 32 guaranteed

        // ---- exact fp32 keys for pool members (identical op chain) ----
        unsigned myk = 0xFFFFFFFFu;
        unsigned myj = 0u;                   // sentinel, never selected (m>=32)
        if ((unsigned)lane < m) {
            myj = s_pool[wv][lane];
            const float qx = s_x[myj], qy = s_y[myj], qz = s_z[myj];
            const float sqj = s_sq[myj];
            const float dt = fmaf(pz, qz, fmaf(py, qy, px * qx));
            float d = fmaf(-2.0f, dt, sqi + sqj);
            d = fmaxf(d, 0.0f);
            myk = __builtin_bit_cast(unsigned, d);
        }

        // ---- partial bitonic: 32-sorts + one merge -> bottom-32 unordered ----
        #pragma unroll
        for (int k = 2; k <= 32; k <<= 1) {
            #pragma unroll
            for (int jj = k >> 1; jj >= 1; jj >>= 1) {
                const unsigned ok = (unsigned)__shfl_xor((int)myk, jj, 64);
                const unsigned oj = (unsigned)__shfl_xor((int)myj, jj, 64);
                const bool wantmin = (((lane & k) == 0) == ((lane & jj) == 0));
                const bool less = (myk < ok) || (myk == ok && myj < oj);
                if (less != wantmin) { myk = ok; myj = oj; }
            }
        }
        {   // k=64, jj=32: lanes 0..31 <- the 32 smallest (unordered)
            const unsigned ok = (unsigned)__shfl_xor((int)myk, 32, 64);
            const unsigned oj = (unsigned)__shfl_xor((int)myj, 32, 64);
            const bool wantmin = ((lane & 32) == 0);
            const bool less = (myk < ok) || (myk == ok && myj < oj);
            if (less != wantmin) { myk = ok; myj = oj; }
        }

        // ---- epilogue: lane = channel e; max over the 32 selected ----
        float dx = 0.f, dy = 0.f, dz = 0.f;
        if (lane < KNN) {
            dx = s_x[myj] - px; dy = s_y[myj] - py; dz = s_z[myj] - pz;
        }
        const float basev = tbv + pbv + fmaf(pw2, pz, fmaf(pw1, py, pw0 * px));
        float mx = -3.0e38f;
        #pragma unroll
        for (int t = 0; t < KNN; ++t) {
            const float ndx = __builtin_bit_cast(float, __builtin_amdgcn_readlane(__builtin_bit_cast(int, dx), t));
            const float ndy = __builtin_bit_cast(float, __builtin_amdgcn_readlane(__builtin_bit_cast(int, dy), t));
            const float ndz = __builtin_bit_cast(float, __builtin_amdgcn_readlane(__builtin_bit_cast(int, dz), t));
            const float proj = fmaf(tw2, ndz, fmaf(tw1, ndy, tw0 * ndx));
            mx = fmaxf(mx, proj);
        }
        out[(((size_t)b * NPTS + (size_t)i) << 6) + lane] = mx + basev;
    }
}

extern "C" void kernel_launch(void* const* d_in, const int* in_sizes, int n_in,
                              void* d_out, int out_size, void* d_ws, size_t ws_size,
                              hipStream_t stream) {
    const float* x  = (const float*)d_in[0];
    const float* tw = (const float*)d_in[1];
    const float* tb = (const float*)d_in[2];
    const float* pw = (const float*)d_in[3];
    const float* pb = (const float*)d_in[4];
    float* out = (float*)d_out;

    dim3 grid(8 * (NPTS / 32));   // 1024 WGs: 128 per batch, 32 points each
    dim3 block(512);
    hipLaunchKernelGGL(edgeconv_knn_kernel, grid, block, 0, stream,
                       x, tw, tb, pw, pb, out);
}